// Round 8
// baseline (362.692 us; speedup 1.0000x reference)
//
#include <hip/hip_runtime.h>
#include <math.h>

#define D 128
#define B_SZ 1024
#define KNB 200
#define AHW 392   // [q|h|r] LDS stride (halves): 196 dw, %32=4 -> cheap 2-way pairs
#define PW 1048   // P LDS stride (halves)

typedef _Float16 half8 __attribute__((ext_vector_type(8)));
typedef float floatx4 __attribute__((ext_vector_type(4)));

__device__ __forceinline__ float sigmoid_f(float x) { return 1.f / (1.f + __expf(-x)); }
__device__ __forceinline__ float tanh_fast(float x) { return 1.f - 2.f / (__expf(2.f * x) + 1.f); }

__device__ __forceinline__ half8 h8zero() {
    half8 z;
    #pragma unroll
    for (int i = 0; i < 8; ++i) z[i] = (_Float16)0.f;
    return z;
}

// ---------------------------------------------------------------------------
// Kernel 1: gather+sum, GCN linear, support encoder, query gather.
// One block per batch row b, 512 threads. (Known wall: ~1.25 TB/s random.)
// Blocks 0..95 additionally convert LSTM weights to fp16 in CONCATENATED
// layout: w16[row][0:128] = w_ih[row], w16[row][128:384] = w_hh[row]
// (row = 0..1023). Gives the gates GEMM one uniform K=384 stream.
// ---------------------------------------------------------------------------
__global__ __launch_bounds__(512) void k_support(
    const int* __restrict__ relations, const int* __restrict__ entities,
    const int* __restrict__ query, const float* __restrict__ emb,
    const float* __restrict__ gcn_w, const float* __restrict__ gcn_b,
    const float* __restrict__ p1_w, const float* __restrict__ p1_b,
    const float* __restrict__ p2_w, const float* __restrict__ p2_b,
    const float* __restrict__ ln_a, const float* __restrict__ ln_b,
    const float* __restrict__ w_ih, const float* __restrict__ w_hh,
    _Float16* __restrict__ w16,
    float* __restrict__ sg, _Float16* __restrict__ sgH, _Float16* __restrict__ sgT,
    float* __restrict__ qb, _Float16* __restrict__ qbH)
{
    __shared__ int idxs[2 * KNB];
    __shared__ __align__(16) float part[16][132];
    __shared__ __align__(16) float S[2 * D];
    __shared__ __align__(16) float sup[D];
    __shared__ __align__(16) float hid[2 * D];
    __shared__ __align__(16) float zv[D];
    __shared__ float red2[2];

    const int b = blockIdx.x;
    const int t = threadIdx.x;

    // ---- folded weight conversion (96 blocks x 512 thr x 8 floats = 393216)
    if (b < 96) {
        const int i8 = (b * 512 + t) * 8;
        const float* src;
        _Float16* dst;
        if (i8 < 131072) {
            const int row = i8 >> 7, col = i8 & 127;
            src = w_ih + i8;
            dst = w16 + (size_t)row * 384 + col;
        } else {
            const int j = i8 - 131072;
            const int row = j >> 8, col = j & 255;
            src = w_hh + j;
            dst = w16 + (size_t)row * 384 + 128 + col;
        }
        float4 v0 = *(const float4*)src;
        float4 v1 = *(const float4*)(src + 4);
        half8 h;
        h[0] = (_Float16)v0.x; h[1] = (_Float16)v0.y; h[2] = (_Float16)v0.z; h[3] = (_Float16)v0.w;
        h[4] = (_Float16)v1.x; h[5] = (_Float16)v1.y; h[6] = (_Float16)v1.z; h[7] = (_Float16)v1.w;
        *(half8*)dst = h;
    }

    if (t < KNB) idxs[t] = relations[b * KNB + t];
    else if (t < 2 * KNB) idxs[t] = entities[b * KNB + (t - KNB)];
    __syncthreads();

    {
        const int g = t >> 5, c4 = (t & 31) * 4;
        const int* mi = &idxs[(g >> 3) * KNB];
        float4 a4 = make_float4(0.f, 0.f, 0.f, 0.f);
        #pragma unroll 5
        for (int k = (g & 7); k < KNB; k += 8) {
            float4 v = *(const float4*)&emb[(size_t)mi[k] * D + c4];
            a4.x += v.x; a4.y += v.y; a4.z += v.z; a4.w += v.w;
        }
        *(float4*)&part[g][c4] = a4;
    }
    __syncthreads();
    if (t < 2 * D) {
        const int half = t >> 7, c = t & 127;
        float s = 0.f;
        #pragma unroll
        for (int j = 0; j < 8; ++j) s += part[half * 8 + j][c];
        S[t] = s;
    }
    __syncthreads();

    if (t < D) {
        const float4* w4 = (const float4*)(gcn_w + t * 2 * D);
        float dot = 0.f;
        #pragma unroll 8
        for (int f = 0; f < 2 * D / 4; ++f) {
            float4 w = w4[f];
            float4 s = *(const float4*)&S[f * 4];
            dot += w.x * s.x + w.y * s.y + w.z * s.z + w.w * s.w;
        }
        float v = (dot + 200.f * gcn_b[t]) * (1.f / 1024.f);  // num_neighbors = B = 1024
        sup[t] = tanhf(v);
    }
    __syncthreads();

    if (t < 2 * D) {
        const float4* w4 = (const float4*)(p1_w + t * D);
        float dot = 0.f;
        #pragma unroll 8
        for (int f = 0; f < D / 4; ++f) {
            float4 w = w4[f];
            float4 s = *(const float4*)&sup[f * 4];
            dot += w.x * s.x + w.y * s.y + w.z * s.z + w.w * s.w;
        }
        float h = dot + p1_b[t];
        hid[t] = h > 0.f ? h : 0.f;
    }
    __syncthreads();

    if (t < D) {
        const float4* w4 = (const float4*)(p2_w + t * 2 * D);
        float dot = 0.f;
        #pragma unroll 8
        for (int f = 0; f < 2 * D / 4; ++f) {
            float4 w = w4[f];
            float4 s = *(const float4*)&hid[f * 4];
            dot += w.x * s.x + w.y * s.y + w.z * s.z + w.w * s.w;
        }
        zv[t] = dot + p2_b[t] + sup[t];
    }
    __syncthreads();

    if (t < 64) {
        float x0 = zv[t], x1 = zv[t + 64];
        float s = x0 + x1;
        for (int off = 32; off; off >>= 1) s += __shfl_down(s, off);
        float mu = __shfl(s, 0) * (1.f / 128.f);
        float d0 = x0 - mu, d1 = x1 - mu;
        float v = d0 * d0 + d1 * d1;
        for (int off = 32; off; off >>= 1) v += __shfl_down(v, off);
        v = __shfl(v, 0);
        if (t == 0) { red2[0] = mu; red2[1] = sqrtf(v * (1.f / 127.f)); }
    }
    __syncthreads();
    if (t < D) {
        float mu = red2[0], sigma = red2[1];
        float val = (zv[t] - mu) / (sigma + 1e-3f) * ln_a[t] + ln_b[t];
        sg[b * D + t] = val;
        sgH[b * D + t] = (_Float16)val;
        sgT[t * B_SZ + b] = (_Float16)val;
        float qv = emb[(size_t)query[b] * D + t];
        qb[b * D + t] = qv;
        qbH[b * D + t] = (_Float16)qv;
    }
}

// ---------------------------------------------------------------------------
// Kernel 2: FUSED recurrence, ILP-restructured. 128 blocks x 8 rows, 512 thr.
// r7 postmortem: phases were chains of serialized (ds_read ~120cy / L2-load
// ~200cy -> MFMA) units: gates = 8 sequential 12-iter loops, r = one 32-deep
// chain. This version: every GEMM is ks-outer with ALL independent chains
// live (gates 8, scores 8, r 4), ping-pong double-buffered operands (no movs,
// no dynamic reg indexing), A-operand read once per ks. waves_per_eu(2)
// declares the true occupancy (8 waves/block, 1 block/CU) so the allocator
// may use ~150 VGPRs without spilling (r7: demand-based alloc, 256 budget).
// ---------------------------------------------------------------------------
__global__ __launch_bounds__(512)
__attribute__((amdgpu_waves_per_eu(2)))
void k_lstm(
    const _Float16* __restrict__ qbH, const float* __restrict__ qb,
    const _Float16* __restrict__ sgH, const _Float16* __restrict__ sgT,
    const float* __restrict__ sg, const _Float16* __restrict__ w16,
    const float* __restrict__ b_ih, const float* __restrict__ b_hh,
    float* __restrict__ out)
{
    __shared__ _Float16 Ah[16 * AHW];   // rows 0-7 live; [0:128]=q,[128:256]=h,[256:384]=r
    __shared__ _Float16 P[16 * PW];     // rows 8-15 zero
    __shared__ float qF[8][132];
    __shared__ float hF[8][132];
    __shared__ float pm[8][12];         // per-wave row-max partials
    __shared__ float ps[8][12];         // per-wave row-sum partials

    const int t = threadIdx.x;          // 0..511
    const int w = t >> 6, lane = t & 63;
    const int m = lane & 15, quad = lane >> 4;
    const int b0 = blockIdx.x * 8;

    // ---- prologue: zero Ah (all) and P rows 8..15, then stage q
    for (int i = t; i < 16 * AHW / 8; i += 512) *(half8*)&Ah[i * 8] = h8zero();
    for (int i = t; i < 8 * PW / 8; i += 512) *(half8*)&P[8 * PW + i * 8] = h8zero();
    __syncthreads();
    if (t < 128) {
        const int row = t >> 4, c = (t & 15) * 8;
        *(half8*)&Ah[row * AHW + c] = *(const half8*)&qbH[(size_t)(b0 + row) * D + c];
    }
    if (t < 256) {
        const int row = t >> 5, c = (t & 31) * 4;
        *(float4*)&qF[row][c] = *(const float4*)&qb[(size_t)(b0 + row) * D + c];
    }

    // ---- persistent per-thread state
    float cregA[4] = {0.f, 0.f, 0.f, 0.f};   // c, units w*16+m
    float cregB[4] = {0.f, 0.f, 0.f, 0.f};   // c, units (w+8)*16+m
    float bi[8];                              // biases, constant across steps
    const _Float16* wp[8];                    // gates weight row pointers
    #pragma unroll
    for (int c = 0; c < 8; ++c) {
        const int unit = (w + (c >> 2) * 8) * 16 + m;
        bi[c] = b_ih[(c & 3) * 256 + unit] + b_hh[(c & 3) * 256 + unit];
        wp[c] = w16 + (size_t)((c & 3) * 256 + unit) * 384 + quad * 8;
    }
    __syncthreads();

    #pragma unroll 1
    for (int s = 0; s < 4; ++s) {
        float sinvd[4] = {1.f, 1.f, 1.f, 1.f};
        if (s > 0) {
            // ---- scores: 8 independent chains (j-tiles w*8..w*8+7), ping-pong K
            floatx4 a2[8];
            #pragma unroll
            for (int i = 0; i < 8; ++i)
                #pragma unroll
                for (int z = 0; z < 4; ++z) a2[i][z] = 0.f;
            {
                const _Float16* sp[8];
                #pragma unroll
                for (int i = 0; i < 8; ++i)
                    sp[i] = sgH + (size_t)((w * 8 + i) * 16 + m) * D + quad * 8;
                half8 sA[8], sB[8];
                #pragma unroll
                for (int i = 0; i < 8; ++i) sA[i] = *(const half8*)(sp[i]);
                half8 a0 = *(const half8*)&Ah[m * AHW + 128 + quad * 8];
                half8 a1;
                #pragma unroll 1
                for (int kk = 0; kk < 2; ++kk) {
                    const int ks = kk * 2;
                    #pragma unroll
                    for (int i = 0; i < 8; ++i) sB[i] = *(const half8*)(sp[i] + (ks + 1) * 32);
                    a1 = *(const half8*)&Ah[m * AHW + 128 + (ks + 1) * 32 + quad * 8];
                    #pragma unroll
                    for (int i = 0; i < 8; ++i)
                        a2[i] = __builtin_amdgcn_mfma_f32_16x16x32_f16(a0, sA[i], a2[i], 0, 0, 0);
                    if (kk < 1) {
                        #pragma unroll
                        for (int i = 0; i < 8; ++i) sA[i] = *(const half8*)(sp[i] + (ks + 2) * 32);
                        a0 = *(const half8*)&Ah[m * AHW + 128 + (ks + 2) * 32 + quad * 8];
                    }
                    #pragma unroll
                    for (int i = 0; i < 8; ++i)
                        a2[i] = __builtin_amdgcn_mfma_f32_16x16x32_f16(a1, sB[i], a2[i], 0, 0, 0);
                }
            }

            // ---- per-wave row-max
            float mx[4];
            #pragma unroll
            for (int rr = 0; rr < 4; ++rr) {
                float v0 = fmaxf(fmaxf(a2[0][rr], a2[1][rr]), fmaxf(a2[2][rr], a2[3][rr]));
                float v1 = fmaxf(fmaxf(a2[4][rr], a2[5][rr]), fmaxf(a2[6][rr], a2[7][rr]));
                mx[rr] = fmaxf(v0, v1);
            }
            #pragma unroll
            for (int off = 1; off <= 8; off <<= 1)
                #pragma unroll
                for (int rr = 0; rr < 4; ++rr)
                    mx[rr] = fmaxf(mx[rr], __shfl_xor(mx[rr], off));
            if (m == 0) {
                #pragma unroll
                for (int rr = 0; rr < 4; ++rr) {
                    const int row = quad * 4 + rr;
                    if (row < 8) pm[w][row] = mx[rr];
                }
            }
            __syncthreads();   // BAR1

            // ---- global row-max (redundant), exp, P write, sum partials
            float gm[4];
            #pragma unroll
            for (int rr = 0; rr < 4; ++rr) {
                const int row = quad * 4 + rr;
                float mm = -1e30f;
                if (row < 8) {
                    #pragma unroll
                    for (int ww = 0; ww < 8; ++ww) mm = fmaxf(mm, pm[ww][row]);
                }
                gm[rr] = mm;
            }
            float sl[4] = {0.f, 0.f, 0.f, 0.f};
            #pragma unroll
            for (int i = 0; i < 8; ++i) {
                const int col = (w * 8 + i) * 16 + m;
                #pragma unroll
                for (int rr = 0; rr < 4; ++rr) {
                    const int row = quad * 4 + rr;
                    if (row < 8) {
                        float e = __expf(a2[i][rr] - gm[rr]);
                        P[row * PW + col] = (_Float16)e;
                        sl[rr] += e;
                    }
                }
            }
            #pragma unroll
            for (int off = 1; off <= 8; off <<= 1)
                #pragma unroll
                for (int rr = 0; rr < 4; ++rr)
                    sl[rr] += __shfl_xor(sl[rr], off);
            if (m == 0) {
                #pragma unroll
                for (int rr = 0; rr < 4; ++rr) {
                    const int row = quad * 4 + rr;
                    if (row < 8) ps[w][row] = sl[rr];
                }
            }
            __syncthreads();   // BAR2

            #pragma unroll
            for (int rr = 0; rr < 4; ++rr) {
                const int row = quad * 4 + rr;
                float ss = 1.f;
                if (row < 8) {
                    ss = 0.f;
                    #pragma unroll
                    for (int ww = 0; ww < 8; ++ww) ss += ps[ww][row];
                }
                sinvd[rr] = 1.f / ss;
            }

            // ---- r: 4 independent chains, prefetch 4 slots ahead
            {
                const _Float16* tb = sgT + (size_t)(w * 16 + m) * B_SZ + quad * 8;
                const int pbase = m * PW + quad * 8;
                floatx4 rc0, rc1, rc2, rc3;
                #pragma unroll
                for (int z = 0; z < 4; ++z) { rc0[z] = 0.f; rc1[z] = 0.f; rc2[z] = 0.f; rc3[z] = 0.f; }
                half8 tA = *(const half8*)(tb);
                half8 pA = *(const half8*)&P[pbase];
                half8 tB = *(const half8*)(tb + 32);
                half8 pB = *(const half8*)&P[pbase + 32];
                half8 tC = *(const half8*)(tb + 64);
                half8 pC = *(const half8*)&P[pbase + 64];
                half8 tD = *(const half8*)(tb + 96);
                half8 pD = *(const half8*)&P[pbase + 96];
                #pragma unroll 1
                for (int kk = 0; kk < 8; ++kk) {
                    const int ks = kk * 4;
                    rc0 = __builtin_amdgcn_mfma_f32_16x16x32_f16(pA, tA, rc0, 0, 0, 0);
                    if (kk < 7) { tA = *(const half8*)(tb + (ks + 4) * 32); pA = *(const half8*)&P[pbase + (ks + 4) * 32]; }
                    rc1 = __builtin_amdgcn_mfma_f32_16x16x32_f16(pB, tB, rc1, 0, 0, 0);
                    if (kk < 7) { tB = *(const half8*)(tb + (ks + 5) * 32); pB = *(const half8*)&P[pbase + (ks + 5) * 32]; }
                    rc2 = __builtin_amdgcn_mfma_f32_16x16x32_f16(pC, tC, rc2, 0, 0, 0);
                    if (kk < 7) { tC = *(const half8*)(tb + (ks + 6) * 32); pC = *(const half8*)&P[pbase + (ks + 6) * 32]; }
                    rc3 = __builtin_amdgcn_mfma_f32_16x16x32_f16(pD, tD, rc3, 0, 0, 0);
                    if (kk < 7) { tD = *(const half8*)(tb + (ks + 7) * 32); pD = *(const half8*)&P[pbase + (ks + 7) * 32]; }
                }
                #pragma unroll
                for (int rr = 0; rr < 4; ++rr) {
                    const int row = quad * 4 + rr;
                    if (row < 8) {
                        float rv = (rc0[rr] + rc1[rr] + rc2[rr] + rc3[rr]) * sinvd[rr];
                        Ah[row * AHW + 256 + w * 16 + m] = (_Float16)rv;
                    }
                }
            }
            __syncthreads();   // BAR3 (r visible to gates)
        }

        // ---- gates: acc = [q|h|r] @ w16cat^T, K=384, 8 chains ks-outer
        floatx4 acc[8];
        #pragma unroll
        for (int c = 0; c < 8; ++c)
            #pragma unroll
            for (int z = 0; z < 4; ++z) acc[c][z] = 0.f;
        {
            half8 wA[8], wB[8];
            #pragma unroll
            for (int c = 0; c < 8; ++c) wA[c] = *(const half8*)(wp[c]);
            half8 a0 = *(const half8*)&Ah[m * AHW + quad * 8];
            half8 a1;
            #pragma unroll 1
            for (int kk = 0; kk < 6; ++kk) {
                const int ks = kk * 2;
                #pragma unroll
                for (int c = 0; c < 8; ++c) wB[c] = *(const half8*)(wp[c] + (ks + 1) * 32);
                a1 = *(const half8*)&Ah[m * AHW + (ks + 1) * 32 + quad * 8];
                #pragma unroll
                for (int c = 0; c < 8; ++c)
                    acc[c] = __builtin_amdgcn_mfma_f32_16x16x32_f16(a0, wA[c], acc[c], 0, 0, 0);
                if (kk < 5) {
                    #pragma unroll
                    for (int c = 0; c < 8; ++c) wA[c] = *(const half8*)(wp[c] + (ks + 2) * 32);
                    a0 = *(const half8*)&Ah[m * AHW + (ks + 2) * 32 + quad * 8];
                }
                #pragma unroll
                for (int c = 0; c < 8; ++c)
                    acc[c] = __builtin_amdgcn_mfma_f32_16x16x32_f16(a1, wB[c], acc[c], 0, 0, 0);
            }
        }

        // ---- pointwise (lower half -> h; upper half -> c only)
        float hregA[4];
        #pragma unroll
        for (int rr = 0; rr < 4; ++rr) {
            float gi = acc[0][rr] + bi[0];
            float gf = acc[1][rr] + bi[1];
            float gg = acc[2][rr] + bi[2];
            float go = acc[3][rr] + bi[3];
            float cn = sigmoid_f(gf) * cregA[rr] + sigmoid_f(gi) * tanh_fast(gg);
            cregA[rr] = cn;
            hregA[rr] = sigmoid_f(go) * tanh_fast(cn);
            float gi1 = acc[4][rr] + bi[4];
            float gf1 = acc[5][rr] + bi[5];
            float gg1 = acc[6][rr] + bi[6];
            float cn1 = sigmoid_f(gf1) * cregB[rr] + sigmoid_f(gi1) * tanh_fast(gg1);
            cregB[rr] = cn1;   // o-gate of upper units never observed (h_[:, D:] discarded)
        }
        __syncthreads();   // BAR4: all Ah reads complete before h overwrite

        {
            const int unit = w * 16 + m;   // 0..127
            #pragma unroll
            for (int rr = 0; rr < 4; ++rr) {
                const int row = quad * 4 + rr;
                if (row < 8) {
                    float ho = qF[row][unit] + hregA[rr];
                    Ah[row * AHW + 128 + unit] = (_Float16)ho;
                    hF[row][unit] = ho;
                }
            }
        }
        __syncthreads();   // BAR5: new h visible
    }

    // ---- cosine: wave w -> row w (8 rows)
    {
        const int row = w;
        float a0 = hF[row][lane], a1 = hF[row][lane + 64];
        float s0 = sg[(size_t)(b0 + row) * D + lane], s1 = sg[(size_t)(b0 + row) * D + lane + 64];
        float cr = a0 * s0 + a1 * s1;
        float n1 = a0 * a0 + a1 * a1;
        float n2 = s0 * s0 + s1 * s1;
        for (int off = 32; off; off >>= 1) {
            cr += __shfl_down(cr, off);
            n1 += __shfl_down(n1, off);
            n2 += __shfl_down(n2, off);
        }
        if (lane == 0) out[b0 + row] = cr / sqrtf(n1 * n2);
    }
}

// ---------------------------------------------------------------------------
extern "C" void kernel_launch(void* const* d_in, const int* in_sizes, int n_in,
                              void* d_out, int out_size, void* d_ws, size_t ws_size,
                              hipStream_t stream)
{
    const int*   relations = (const int*)d_in[0];
    const int*   entities  = (const int*)d_in[1];
    const int*   query     = (const int*)d_in[2];
    const float* emb       = (const float*)d_in[3];
    const float* gcn_w     = (const float*)d_in[4];
    const float* gcn_b     = (const float*)d_in[5];
    const float* p1_w      = (const float*)d_in[6];
    const float* p1_b      = (const float*)d_in[7];
    const float* p2_w      = (const float*)d_in[8];
    const float* p2_b      = (const float*)d_in[9];
    const float* ln_a      = (const float*)d_in[10];
    const float* ln_b      = (const float*)d_in[11];
    const float* w_ih      = (const float*)d_in[12];
    const float* w_hh      = (const float*)d_in[13];
    const float* b_ih      = (const float*)d_in[14];
    const float* b_hh      = (const float*)d_in[15];

    // Workspace layout (float-slot offsets)
    float* ws = (float*)d_ws;
    float*     sg   = ws;                          // 131072
    float*     qb   = ws + 131072;                 // 131072
    _Float16*  sgH  = (_Float16*)(ws + 262144);    // 65536 float slots
    _Float16*  sgT  = (_Float16*)(ws + 327680);
    _Float16*  qbH  = (_Float16*)(ws + 393216);
    _Float16*  w16  = (_Float16*)(ws + 458752);    // 196608 float slots (1024x384 fp16)
    // end: 655360 floats = 2.6 MB

    k_support<<<dim3(B_SZ), dim3(512), 0, stream>>>(
        relations, entities, query, emb, gcn_w, gcn_b,
        p1_w, p1_b, p2_w, p2_b, ln_a, ln_b,
        w_ih, w_hh, w16,
        sg, sgH, sgT, qb, qbH);
    k_lstm<<<dim3(B_SZ / 8), dim3(512), 0, stream>>>(
        qbH, qb, sgH, sgT, sg, w16, b_ih, b_hh, (float*)d_out);
}

// Round 9
// 302.891 us; speedup vs baseline: 1.1974x; 1.1974x over previous
//
#include <hip/hip_runtime.h>
#include <math.h>

#define D 128
#define B_SZ 1024
#define KNB 200
#define AWQ 136   // q LDS stride (halves) in k_gq      (68 dw %32=4 -> 2-way, free)
#define AWG 264   // [h|r] LDS stride (halves) in gates (132 dw %32=4 -> 2-way, free)
#define HW 136    // h LDS stride (halves) in attn
#define SCW 1028  // scores LDS stride (f32)
#define PW 1048   // P LDS stride (halves) (524 dw %32=12 -> 2-way pairs)

typedef _Float16 half8 __attribute__((ext_vector_type(8)));
typedef _Float16 half4 __attribute__((ext_vector_type(4)));
typedef float floatx4 __attribute__((ext_vector_type(4)));

__device__ __forceinline__ float sigmoid_f(float x) { return 1.f / (1.f + __expf(-x)); }
__device__ __forceinline__ float tanh_fast(float x) { return 1.f - 2.f / (__expf(2.f * x) + 1.f); }

// ---------------------------------------------------------------------------
// Kernel 1: gather+sum, GCN linear, support encoder, query gather.
// One block per batch row b, 512 threads. (Known wall: ~1.25 TB/s random.)
// Blocks 0..95 additionally convert the LSTM weights to fp16 (split layout):
// w16[0:131072] = w_ih [1024][128]; w16[131072:] = w_hh [1024][256].
// (Folded former k_cvtw launch — validated in r6-r8.)
// ---------------------------------------------------------------------------
__global__ __launch_bounds__(512) void k_support(
    const int* __restrict__ relations, const int* __restrict__ entities,
    const int* __restrict__ query, const float* __restrict__ emb,
    const float* __restrict__ gcn_w, const float* __restrict__ gcn_b,
    const float* __restrict__ p1_w, const float* __restrict__ p1_b,
    const float* __restrict__ p2_w, const float* __restrict__ p2_b,
    const float* __restrict__ ln_a, const float* __restrict__ ln_b,
    const float* __restrict__ w_ih, const float* __restrict__ w_hh,
    _Float16* __restrict__ w16,
    float* __restrict__ sg, _Float16* __restrict__ sgH, _Float16* __restrict__ sgT,
    float* __restrict__ qb, _Float16* __restrict__ qbH)
{
    __shared__ int idxs[2 * KNB];
    __shared__ __align__(16) float part[16][132];
    __shared__ __align__(16) float S[2 * D];
    __shared__ __align__(16) float sup[D];
    __shared__ __align__(16) float hid[2 * D];
    __shared__ __align__(16) float zv[D];
    __shared__ float red2[2];

    const int b = blockIdx.x;
    const int t = threadIdx.x;

    // ---- folded weight conversion (96 blocks x 512 thr x 8 floats = 393216)
    if (b < 96) {
        const int i8 = (b * 512 + t) * 8;
        const float* src = (i8 < 131072) ? (w_ih + i8) : (w_hh + (i8 - 131072));
        float4 v0 = *(const float4*)src;
        float4 v1 = *(const float4*)(src + 4);
        half8 h;
        h[0] = (_Float16)v0.x; h[1] = (_Float16)v0.y; h[2] = (_Float16)v0.z; h[3] = (_Float16)v0.w;
        h[4] = (_Float16)v1.x; h[5] = (_Float16)v1.y; h[6] = (_Float16)v1.z; h[7] = (_Float16)v1.w;
        *(half8*)&w16[i8] = h;
    }

    if (t < KNB) idxs[t] = relations[b * KNB + t];
    else if (t < 2 * KNB) idxs[t] = entities[b * KNB + (t - KNB)];
    __syncthreads();

    {
        const int g = t >> 5, c4 = (t & 31) * 4;
        const int* mi = &idxs[(g >> 3) * KNB];
        float4 a4 = make_float4(0.f, 0.f, 0.f, 0.f);
        #pragma unroll 5
        for (int k = (g & 7); k < KNB; k += 8) {
            float4 v = *(const float4*)&emb[(size_t)mi[k] * D + c4];
            a4.x += v.x; a4.y += v.y; a4.z += v.z; a4.w += v.w;
        }
        *(float4*)&part[g][c4] = a4;
    }
    __syncthreads();
    if (t < 2 * D) {
        const int half = t >> 7, c = t & 127;
        float s = 0.f;
        #pragma unroll
        for (int j = 0; j < 8; ++j) s += part[half * 8 + j][c];
        S[t] = s;
    }
    __syncthreads();

    if (t < D) {
        const float4* w4 = (const float4*)(gcn_w + t * 2 * D);
        float dot = 0.f;
        #pragma unroll 8
        for (int f = 0; f < 2 * D / 4; ++f) {
            float4 w = w4[f];
            float4 s = *(const float4*)&S[f * 4];
            dot += w.x * s.x + w.y * s.y + w.z * s.z + w.w * s.w;
        }
        float v = (dot + 200.f * gcn_b[t]) * (1.f / 1024.f);  // num_neighbors = B = 1024
        sup[t] = tanhf(v);
    }
    __syncthreads();

    if (t < 2 * D) {
        const float4* w4 = (const float4*)(p1_w + t * D);
        float dot = 0.f;
        #pragma unroll 8
        for (int f = 0; f < D / 4; ++f) {
            float4 w = w4[f];
            float4 s = *(const float4*)&sup[f * 4];
            dot += w.x * s.x + w.y * s.y + w.z * s.z + w.w * s.w;
        }
        float h = dot + p1_b[t];
        hid[t] = h > 0.f ? h : 0.f;
    }
    __syncthreads();

    if (t < D) {
        const float4* w4 = (const float4*)(p2_w + t * 2 * D);
        float dot = 0.f;
        #pragma unroll 8
        for (int f = 0; f < 2 * D / 4; ++f) {
            float4 w = w4[f];
            float4 s = *(const float4*)&hid[f * 4];
            dot += w.x * s.x + w.y * s.y + w.z * s.z + w.w * s.w;
        }
        zv[t] = dot + p2_b[t] + sup[t];
    }
    __syncthreads();

    if (t < 64) {
        float x0 = zv[t], x1 = zv[t + 64];
        float s = x0 + x1;
        for (int off = 32; off; off >>= 1) s += __shfl_down(s, off);
        float mu = __shfl(s, 0) * (1.f / 128.f);
        float d0 = x0 - mu, d1 = x1 - mu;
        float v = d0 * d0 + d1 * d1;
        for (int off = 32; off; off >>= 1) v += __shfl_down(v, off);
        v = __shfl(v, 0);
        if (t == 0) { red2[0] = mu; red2[1] = sqrtf(v * (1.f / 127.f)); }
    }
    __syncthreads();
    if (t < D) {
        float mu = red2[0], sigma = red2[1];
        float val = (zv[t] - mu) / (sigma + 1e-3f) * ln_a[t] + ln_b[t];
        sg[b * D + t] = val;
        sgH[b * D + t] = (_Float16)val;
        sgT[t * B_SZ + b] = (_Float16)val;
        float qv = emb[(size_t)query[b] * D + t];
        qb[b * D + t] = qv;
        qbH[b * D + t] = (_Float16)qv;
    }
}

// ---------------------------------------------------------------------------
// Kernel 2: gq = q @ w_ih^T (raw, pre-bias, stored f32) + step-0 LSTM
// pointwise (c=0). Grid (16,16), 256 threads (4 waves x 16 rows).
// ---------------------------------------------------------------------------
__global__ __launch_bounds__(256) void k_gq(
    const _Float16* __restrict__ qbH, const _Float16* __restrict__ w16,
    const float* __restrict__ b_ih, const float* __restrict__ b_hh,
    const float* __restrict__ qb, float* __restrict__ gqB,
    float* __restrict__ cbuf, float* __restrict__ hout, _Float16* __restrict__ houtH)
{
    __shared__ _Float16 Ah[64 * AWQ];
    __shared__ _Float16 Bh[2][4][16][40];

    const int t = threadIdx.x;
    const int b0 = blockIdx.x * 64;
    const int n0 = blockIdx.y * 16;
    const int lane = t & 63, wv = t >> 6;
    const int m = lane & 15, quad = lane >> 4;

    {   // stage q (fp16 copies)
        const int row = t >> 2, gr = b0 + row;
        #pragma unroll
        for (int i = 0; i < 4; ++i) {
            const int c = (t & 3) * 8 + i * 32;
            *(half8*)&Ah[row * AWQ + c] = *(const half8*)&qbH[gr * D + c];
        }
    }
    const int sg_g = t >> 6, sg_u = (t >> 2) & 15, sg_kq = (t & 3) * 8;
    auto stage_b = [&](int ks, int buf) {
        const int grow = sg_g * 256 + n0 + sg_u;
        *(half8*)&Bh[buf][sg_g][sg_u][sg_kq] = *(const half8*)&w16[grow * D + ks * 32 + sg_kq];
    };
    stage_b(0, 0);
    __syncthreads();

    floatx4 acc[4];
    #pragma unroll
    for (int g = 0; g < 4; ++g)
        #pragma unroll
        for (int i = 0; i < 4; ++i) acc[g][i] = 0.f;

    for (int ks = 0; ks < 4; ++ks) {
        if (ks + 1 < 4) stage_b(ks + 1, (ks + 1) & 1);
        half8 a = *(const half8*)&Ah[(wv * 16 + m) * AWQ + ks * 32 + quad * 8];
        #pragma unroll
        for (int g = 0; g < 4; ++g) {
            half8 bf = *(const half8*)&Bh[ks & 1][g][m][quad * 8];
            acc[g] = __builtin_amdgcn_mfma_f32_16x16x32_f16(a, bf, acc[g], 0, 0, 0);
        }
        __syncthreads();
    }

    const int unit = n0 + m;
    float bi[4];
    #pragma unroll
    for (int g = 0; g < 4; ++g) bi[g] = b_ih[g * 256 + unit] + b_hh[g * 256 + unit];
    #pragma unroll
    for (int rr = 0; rr < 4; ++rr) {
        const int b = b0 + wv * 16 + quad * 4 + rr;
        // store raw gq for steps 1-3
        #pragma unroll
        for (int g = 0; g < 4; ++g) gqB[(size_t)b * 1024 + g * 256 + unit] = acc[g][rr];
        // step-0 pointwise (c = 0)
        float gi = acc[0][rr] + bi[0];
        float gg = acc[2][rr] + bi[2];
        float go = acc[3][rr] + bi[3];
        float cn = sigmoid_f(gi) * tanh_fast(gg);
        cbuf[b * 256 + unit] = cn;
        if (n0 < D) {
            float ho = qb[b * D + unit] + sigmoid_f(go) * tanh_fast(cn);
            hout[b * D + unit] = ho;
            houtH[b * D + unit] = (_Float16)ho;
        }
    }
}

// ---------------------------------------------------------------------------
// Kernel 3: FUSED attention: scores = h@sg^T -> softmax -> r = P@sg (fp16 out).
// 64 blocks x 16 rows, 1024 threads (16 waves). One phase each.
// ---------------------------------------------------------------------------
__global__ __launch_bounds__(1024) void k_attn(
    const _Float16* __restrict__ hH, const _Float16* __restrict__ sgH,
    const _Float16* __restrict__ sgT, _Float16* __restrict__ rH)
{
    __shared__ _Float16 Hh[16 * HW];
    __shared__ float    Sc[16 * SCW];
    __shared__ _Float16 P[16 * PW];
    __shared__ float    sinv[16];
    __shared__ float    rpar[2][16][132];

    const int t = threadIdx.x;
    const int wv = t >> 6, lane = t & 63;
    const int m = lane & 15, quad = lane >> 4;
    const int b0 = blockIdx.x * 16;

    if (t < 256) {
        const int row = t >> 4, c = (t & 15) * 8;
        *(half8*)&Hh[row * HW + c] = *(const half8*)&hH[(b0 + row) * D + c];
    }
    __syncthreads();

    // ---- scores: wave wv -> j-tiles wv*4..+3 (4 independent acc chains)
    {
        floatx4 a2[4];
        #pragma unroll
        for (int i = 0; i < 4; ++i)
            #pragma unroll
            for (int z = 0; z < 4; ++z) a2[i][z] = 0.f;
        #pragma unroll
        for (int ks = 0; ks < 4; ++ks) {
            half8 a = *(const half8*)&Hh[m * HW + ks * 32 + quad * 8];
            #pragma unroll
            for (int i = 0; i < 4; ++i) {
                const int j0 = (wv * 4 + i) * 16;
                half8 bf = *(const half8*)&sgH[(j0 + m) * D + ks * 32 + quad * 8];
                a2[i] = __builtin_amdgcn_mfma_f32_16x16x32_f16(a, bf, a2[i], 0, 0, 0);
            }
        }
        #pragma unroll
        for (int i = 0; i < 4; ++i) {
            const int j0 = (wv * 4 + i) * 16;
            #pragma unroll
            for (int rr = 0; rr < 4; ++rr)
                Sc[(quad * 4 + rr) * SCW + j0 + m] = a2[i][rr];
        }
    }
    __syncthreads();

    // ---- softmax: wave wv owns row wv (64 lanes x 16 cols)
    {
        const int row = wv;
        float vals[16];
        float mm = -1e30f;
        #pragma unroll
        for (int j = 0; j < 16; ++j) {
            vals[j] = Sc[row * SCW + lane + j * 64];
            mm = fmaxf(mm, vals[j]);
        }
        #pragma unroll
        for (int off = 32; off; off >>= 1) mm = fmaxf(mm, __shfl_down(mm, off));
        mm = __shfl(mm, 0);
        float ss = 0.f;
        #pragma unroll
        for (int j = 0; j < 16; ++j) {
            float e = __expf(vals[j] - mm);
            P[row * PW + lane + j * 64] = (_Float16)e;
            ss += e;
        }
        #pragma unroll
        for (int off = 32; off; off >>= 1) ss += __shfl_down(ss, off);
        if (lane == 0) sinv[row] = 1.f / ss;
    }
    __syncthreads();

    // ---- r partials: wave -> (n-tile = wv&7, K-half = wv>>3)
    {
        const int nt = wv & 7, kh = wv >> 3;
        floatx4 a3;
        #pragma unroll
        for (int z = 0; z < 4; ++z) a3[z] = 0.f;
        #pragma unroll
        for (int ks = 0; ks < 16; ++ks) {
            const int kk = kh * 16 + ks;
            half8 a = *(const half8*)&P[m * PW + kk * 32 + quad * 8];
            half8 bf = *(const half8*)&sgT[(nt * 16 + m) * B_SZ + kk * 32 + quad * 8];
            a3 = __builtin_amdgcn_mfma_f32_16x16x32_f16(a, bf, a3, 0, 0, 0);
        }
        #pragma unroll
        for (int rr = 0; rr < 4; ++rr)
            rpar[kh][quad * 4 + rr][nt * 16 + m] = a3[rr];
    }
    __syncthreads();

    // ---- combine + scale -> rH
    {
        const int e = t;
        const int row = e >> 7, col = e & 127;
        float v = (rpar[0][row][col] + rpar[1][row][col]) * sinv[row];
        rH[(b0 + row) * D + col] = (_Float16)v;
    }
    {
        const int e = t + 1024;
        if (e < 2048) {
            const int row = e >> 7, col = e & 127;
            float v = (rpar[0][row][col] + rpar[1][row][col]) * sinv[row];
            rH[(b0 + row) * D + col] = (_Float16)v;
        }
    }
}

// ---------------------------------------------------------------------------
// Kernel 4: gates step s>=1: acc = gq + [h|r] @ w_hh^T (K=256) + pointwise.
// Grid (16,16), 256 threads.
// ---------------------------------------------------------------------------
__global__ __launch_bounds__(256) void k_gates(
    const _Float16* __restrict__ hHin, const _Float16* __restrict__ rH,
    const _Float16* __restrict__ w16, const float* __restrict__ gqB,
    const float* __restrict__ b_ih, const float* __restrict__ b_hh,
    const float* __restrict__ qb, float* __restrict__ cbuf,
    float* __restrict__ hout, _Float16* __restrict__ hHout)
{
    __shared__ _Float16 Ah[64 * AWG];
    __shared__ _Float16 Bh[2][4][16][40];

    const int t = threadIdx.x;
    const int b0 = blockIdx.x * 64;
    const int n0 = blockIdx.y * 16;
    const int lane = t & 63, wv = t >> 6;
    const int m = lane & 15, quad = lane >> 4;

    {   // stage [h|r] (pure fp16 copies)
        const int row = t >> 2, gr = b0 + row;
        #pragma unroll
        for (int i = 0; i < 8; ++i) {
            const int c = (t & 3) * 8 + i * 32;
            half8 h;
            if (c < 128) h = *(const half8*)&hHin[gr * D + c];
            else         h = *(const half8*)&rH[gr * D + (c - 128)];
            *(half8*)&Ah[row * AWG + c] = h;
        }
    }
    const int sg_g = t >> 6, sg_u = (t >> 2) & 15, sg_kq = (t & 3) * 8;
    auto stage_b = [&](int ks, int buf) {
        const int grow = sg_g * 256 + n0 + sg_u;
        *(half8*)&Bh[buf][sg_g][sg_u][sg_kq] =
            *(const half8*)&w16[131072 + grow * 256 + ks * 32 + sg_kq];
    };
    stage_b(0, 0);

    // acc init from gq (global f32, scattered)
    const int unit = n0 + m;
    floatx4 acc[4];
    #pragma unroll
    for (int rr = 0; rr < 4; ++rr) {
        const int b = b0 + wv * 16 + quad * 4 + rr;
        #pragma unroll
        for (int g = 0; g < 4; ++g) acc[g][rr] = gqB[(size_t)b * 1024 + g * 256 + unit];
    }
    __syncthreads();

    for (int ks = 0; ks < 8; ++ks) {
        if (ks + 1 < 8) stage_b(ks + 1, (ks + 1) & 1);
        half8 a = *(const half8*)&Ah[(wv * 16 + m) * AWG + ks * 32 + quad * 8];
        #pragma unroll
        for (int g = 0; g < 4; ++g) {
            half8 bf = *(const half8*)&Bh[ks & 1][g][m][quad * 8];
            acc[g] = __builtin_amdgcn_mfma_f32_16x16x32_f16(a, bf, acc[g], 0, 0, 0);
        }
        __syncthreads();
    }

    float bi[4];
    #pragma unroll
    for (int g = 0; g < 4; ++g) bi[g] = b_ih[g * 256 + unit] + b_hh[g * 256 + unit];
    #pragma unroll
    for (int rr = 0; rr < 4; ++rr) {
        const int b = b0 + wv * 16 + quad * 4 + rr;
        float gi = acc[0][rr] + bi[0];
        float gf = acc[1][rr] + bi[1];
        float gg = acc[2][rr] + bi[2];
        float go = acc[3][rr] + bi[3];
        float cold = cbuf[b * 256 + unit];
        float cn = sigmoid_f(gf) * cold + sigmoid_f(gi) * tanh_fast(gg);
        cbuf[b * 256 + unit] = cn;
        if (n0 < D) {
            float ho = qb[b * D + unit] + sigmoid_f(go) * tanh_fast(cn);
            hout[b * D + unit] = ho;
            hHout[b * D + unit] = (_Float16)ho;
        }
    }
}

// ---------------------------------------------------------------------------
// Kernel 5: cosine similarity per row. One wave per row.
// ---------------------------------------------------------------------------
__global__ __launch_bounds__(64) void k_cosine(
    const float* __restrict__ hout, const float* __restrict__ sg,
    float* __restrict__ out)
{
    const int b = blockIdx.x, t = threadIdx.x;
    float a0 = hout[b * D + t], a1 = hout[b * D + t + 64];
    float s0 = sg[b * D + t], s1 = sg[b * D + t + 64];
    float cr = a0 * s0 + a1 * s1;
    float n1 = a0 * a0 + a1 * a1;
    float n2 = s0 * s0 + s1 * s1;
    for (int off = 32; off; off >>= 1) {
        cr += __shfl_down(cr, off);
        n1 += __shfl_down(n1, off);
        n2 += __shfl_down(n2, off);
    }
    if (t == 0) out[b] = cr / sqrtf(n1 * n2);
}

// ---------------------------------------------------------------------------
extern "C" void kernel_launch(void* const* d_in, const int* in_sizes, int n_in,
                              void* d_out, int out_size, void* d_ws, size_t ws_size,
                              hipStream_t stream)
{
    const int*   relations = (const int*)d_in[0];
    const int*   entities  = (const int*)d_in[1];
    const int*   query     = (const int*)d_in[2];
    const float* emb       = (const float*)d_in[3];
    const float* gcn_w     = (const float*)d_in[4];
    const float* gcn_b     = (const float*)d_in[5];
    const float* p1_w      = (const float*)d_in[6];
    const float* p1_b      = (const float*)d_in[7];
    const float* p2_w      = (const float*)d_in[8];
    const float* p2_b      = (const float*)d_in[9];
    const float* ln_a      = (const float*)d_in[10];
    const float* ln_b      = (const float*)d_in[11];
    const float* w_ih      = (const float*)d_in[12];
    const float* w_hh      = (const float*)d_in[13];
    const float* b_ih      = (const float*)d_in[14];
    const float* b_hh      = (const float*)d_in[15];

    // Workspace layout (float-slot offsets)
    float* ws = (float*)d_ws;
    float*     sg   = ws;                          // 131072
    float*     qb   = ws + 131072;                 // 131072
    float*     hoF  = ws + 262144;                 // 131072 (f32 h_out, final use)
    float*     cb   = ws + 393216;                 // 262144
    float*     gqB  = ws + 655360;                 // 1048576 (1024x1024 f32)
    _Float16*  sgH  = (_Float16*)(ws + 1703936);   // 65536 slots each
    _Float16*  sgT  = (_Float16*)(ws + 1769472);
    _Float16*  qbH  = (_Float16*)(ws + 1835008);
    _Float16*  hHA  = (_Float16*)(ws + 1900544);
    _Float16*  hHB  = (_Float16*)(ws + 1966080);
    _Float16*  rH   = (_Float16*)(ws + 2031616);
    _Float16*  w16  = (_Float16*)(ws + 2097152);   // 196608 slots
    // end: 2293760 floats = 9.2 MB

    k_support<<<dim3(B_SZ), dim3(512), 0, stream>>>(
        relations, entities, query, emb, gcn_w, gcn_b,
        p1_w, p1_b, p2_w, p2_b, ln_a, ln_b,
        w_ih, w_hh, w16,
        sg, sgH, sgT, qb, qbH);

    // step 0: gq + pointwise (c=0) -> hHB
    k_gq<<<dim3(16, 16), dim3(256), 0, stream>>>(
        qbH, w16, b_ih, b_hh, qb, gqB, cb, hoF, hHB);

    // step 1
    k_attn<<<dim3(64), dim3(1024), 0, stream>>>(hHB, sgH, sgT, rH);
    k_gates<<<dim3(16, 16), dim3(256), 0, stream>>>(
        hHB, rH, w16, gqB, b_ih, b_hh, qb, cb, hoF, hHA);
    // step 2
    k_attn<<<dim3(64), dim3(1024), 0, stream>>>(hHA, sgH, sgT, rH);
    k_gates<<<dim3(16, 16), dim3(256), 0, stream>>>(
        hHA, rH, w16, gqB, b_ih, b_hh, qb, cb, hoF, hHB);
    // step 3 (attention of step 4 would be dead; not launched)
    k_attn<<<dim3(64), dim3(1024), 0, stream>>>(hHB, sgH, sgT, rH);
    k_gates<<<dim3(16, 16), dim3(256), 0, stream>>>(
        hHB, rH, w16, gqB, b_ih, b_hh, qb, cb, hoF, hHA);

    k_cosine<<<dim3(B_SZ), dim3(64), 0, stream>>>(hoF, sg, (float*)d_out);
}